// Round 1
// baseline (202.501 us; speedup 1.0000x reference)
//
#include <hip/hip_runtime.h>

typedef unsigned short u16;
typedef unsigned int u32;

typedef __bf16 bf16x8 __attribute__((ext_vector_type(8)));
typedef float f32x4 __attribute__((ext_vector_type(4)));

union V16 { uint4 u; bf16x8 v; u16 s[8]; __bf16 h[8]; };
union F4  { float4 v; float f[4]; };

__device__ __forceinline__ float bf2f(u16 a) {
  union { u32 u; float f; } c; c.u = ((u32)a) << 16; return c.f;
}

#define Z_OFF   131072
#define ZM_OFF  147456
#define ZLV_OFF 163840

// ws layout in uint4 units (decoder weights only; encoder is fused/on-the-fly).
// Fragment packs (b-frag elem j of lane: B[k=s*32+(lane>>4)*8+j][n=t*16+(lane&15)]):
#define B1_OFF 0        // gen1_w: t<20, s<2   -> 2560 uint4
#define B2_OFF 2560     // gen2_w: t<20, s<10  -> 12800 uint4
#define WB4   15360     // W bf16 [512][64]    -> 4096 uint4
#define PACK_TOTAL 19456
#define NENC 16
#define PACK_BLOCKS ((PACK_TOTAL + 319) / 320)   // 61

__device__ __forceinline__ void pack_one(const float* __restrict__ src,
                                         int t, int s, int lane,
                                         int Nsrc, int Ksrc, int rowlen,
                                         uint4* __restrict__ dst) {
  const int n = t * 16 + (lane & 15);
  const int k0 = s * 32 + ((lane >> 4) << 3);
  V16 v;
#pragma unroll
  for (int j = 0; j < 8; ++j) {
    const int k = k0 + j;
    v.h[j] = (n < Nsrc && k < Ksrc) ? (__bf16)src[n * rowlen + k] : (__bf16)0.f;
  }
  *dst = v.u;
}

__device__ __forceinline__ void cvt8(const float* __restrict__ src, uint4* __restrict__ dst) {
  F4 a, b; a.v = *(const float4*)src; b.v = *(const float4*)(src + 4);
  V16 v;
#pragma unroll
  for (int j = 0; j < 4; ++j) { v.h[j] = (__bf16)a.f[j]; v.h[4 + j] = (__bf16)b.f[j]; }
  *dst = v.u;
}

// On-the-fly b-fragment build from an fp32 row-major [N][ld] matrix, B = w^T.
// Elem j of lane = w[n][k0+j], n = (tile col), k0 = s*32 + q*8. Matches pack_one.
__device__ __forceinline__ uint4 mkfrag(const float* __restrict__ w, int n, int k0,
                                        int N, int K, int ld) {
  V16 v;
  if (n < N && k0 + 7 < K) {
    F4 a, b;
    a.v = *(const float4*)(w + n * ld + k0);
    b.v = *(const float4*)(w + n * ld + k0 + 4);
#pragma unroll
    for (int j = 0; j < 4; ++j) { v.h[j] = (__bf16)a.f[j]; v.h[4 + j] = (__bf16)b.f[j]; }
  } else if (n < N) {
#pragma unroll
    for (int j = 0; j < 8; ++j) {
      const int k = k0 + j;
      v.h[j] = (k < K) ? (__bf16)w[n * ld + k] : (__bf16)0.f;
    }
  } else {
    v.u = make_uint4(0u, 0u, 0u, 0u);
  }
  return v.u;
}

// ---------------------------------------------------------------------------
// prep_kernel: blocks [0,16) = fused encoder (16 rows of B each, 5 waves);
//              blocks [16,16+61) = decoder-weight packing (independent).
// The encoder chain is row-independent, so enc1->enc2->heads runs inside one
// WG via LDS with __syncthreads; weights are converted fp32->bf16 on the fly
// with the exact same casts as pack_one (bit-identical numerics).
// ---------------------------------------------------------------------------
__global__ __launch_bounds__(320) void prep_kernel(
    const float* __restrict__ x,   const float* __restrict__ eps,
    const float* __restrict__ e1w, const float* __restrict__ e1b,
    const float* __restrict__ e2w, const float* __restrict__ e2b,
    const float* __restrict__ zmw, const float* __restrict__ zmb,
    const float* __restrict__ zvw, const float* __restrict__ zvb,
    const float* __restrict__ g1w, const float* __restrict__ g2w,
    const float* __restrict__ W,
    uint4* __restrict__ ws4, float* __restrict__ out) {
  __shared__ uint4 xs[16 * 65];      // x tile, bf16 [16][520] as uint4 [16][65] (padded)
  __shared__ u16  h1s[16 * 328];     // h1 tile bf16, padded stride 328
  u16* h2s = (u16*)xs;               // h2 aliases xs after E1 barrier

  const int blk = blockIdx.x;
  const int tid = threadIdx.x;

  if (blk >= NENC) {
    // ---- decoder weight packing ----
    const int idx = (blk - NENC) * 320 + tid;
    if (idx >= PACK_TOTAL) return;
    const int lane = idx & 63;
    if (idx < B2_OFF) {
      const int f = idx >> 6;
      pack_one(g1w, f >> 1, f & 1, lane, 300, 64, 64, ws4 + B1_OFF + idx);
    } else if (idx < WB4) {
      const int f = (idx - B2_OFF) >> 6;
      pack_one(g2w, f / 10, f % 10, lane, 300, 300, 300, ws4 + idx);
    } else {
      const int i = idx - WB4;
      cvt8(W + i * 8, ws4 + WB4 + i);
    }
    return;
  }

  // ---- fused encoder, rows r0..r0+15 ----
  const int u = tid >> 6;            // wave 0..4: owns n-tiles 4u..4u+3
  const int lane = tid & 63;
  const int q = lane >> 4, c = lane & 15;
  const int r0 = blk * 16;

  // stage x -> LDS bf16 (16 rows x 512)
  for (int i = tid; i < 1024; i += 320) {
    const int row = i >> 6, kg = i & 63;
    cvt8(x + (r0 + row) * 512 + kg * 8, &xs[row * 65 + kg]);
  }
  __syncthreads();

  // E1: h1 = ReLU(x @ e1w^T + b), K=512 (16 steps), cols (4u+tt)*16+c
  {
    f32x4 acc[4];
#pragma unroll
    for (int tt = 0; tt < 4; ++tt) acc[tt] = {0.f, 0.f, 0.f, 0.f};
#pragma unroll 4
    for (int s = 0; s < 16; ++s) {
      V16 a; a.u = xs[c * 65 + s * 4 + q];
#pragma unroll
      for (int tt = 0; tt < 4; ++tt) {
        V16 b; b.u = mkfrag(e1w, (4 * u + tt) * 16 + c, s * 32 + q * 8, 300, 512, 512);
        acc[tt] = __builtin_amdgcn_mfma_f32_16x16x32_bf16(a.v, b.v, acc[tt], 0, 0, 0);
      }
    }
#pragma unroll
    for (int tt = 0; tt < 4; ++tt) {
      const int col = (4 * u + tt) * 16 + c;
      const float bias = (col < 300) ? e1b[col] : 0.f;
#pragma unroll
      for (int i = 0; i < 4; ++i) {
        V16 t; t.h[0] = (col < 300) ? (__bf16)fmaxf(acc[tt][i] + bias, 0.f) : (__bf16)0.f;
        h1s[(4 * q + i) * 328 + col] = t.s[0];
      }
    }
  }
  __syncthreads();   // xs reads done -> safe to alias as h2s below

  // E2: h2 = ReLU(h1 @ e2w^T + b), K=320 (10 steps)
  {
    f32x4 acc[4];
#pragma unroll
    for (int tt = 0; tt < 4; ++tt) acc[tt] = {0.f, 0.f, 0.f, 0.f};
#pragma unroll 2
    for (int s = 0; s < 10; ++s) {
      V16 a; a.u = *(const uint4*)&h1s[c * 328 + s * 32 + q * 8];
#pragma unroll
      for (int tt = 0; tt < 4; ++tt) {
        V16 b; b.u = mkfrag(e2w, (4 * u + tt) * 16 + c, s * 32 + q * 8, 300, 300, 300);
        acc[tt] = __builtin_amdgcn_mfma_f32_16x16x32_bf16(a.v, b.v, acc[tt], 0, 0, 0);
      }
    }
#pragma unroll
    for (int tt = 0; tt < 4; ++tt) {
      const int col = (4 * u + tt) * 16 + c;
      const float bias = (col < 300) ? e2b[col] : 0.f;
#pragma unroll
      for (int i = 0; i < 4; ++i) {
        V16 t; t.h[0] = (col < 300) ? (__bf16)fmaxf(acc[tt][i] + bias, 0.f) : (__bf16)0.f;
        h2s[(4 * q + i) * 328 + col] = t.s[0];
      }
    }
  }
  __syncthreads();

  // heads: zm/zlv/z, L=64 -> 4 n-tiles, waves 0..3 (wave 4 idle)
  if (u < 4) {
    f32x4 am = {0.f, 0.f, 0.f, 0.f}, av = {0.f, 0.f, 0.f, 0.f};
#pragma unroll 2
    for (int s = 0; s < 10; ++s) {
      V16 a; a.u = *(const uint4*)&h2s[c * 328 + s * 32 + q * 8];
      V16 bm, bv;
      bm.u = mkfrag(zmw, u * 16 + c, s * 32 + q * 8, 64, 300, 300);
      bv.u = mkfrag(zvw, u * 16 + c, s * 32 + q * 8, 64, 300, 300);
      am = __builtin_amdgcn_mfma_f32_16x16x32_bf16(a.v, bm.v, am, 0, 0, 0);
      av = __builtin_amdgcn_mfma_f32_16x16x32_bf16(a.v, bv.v, av, 0, 0, 0);
    }
    const int col = u * 16 + c;
    const float bm = zmb[col], bv = zvb[col];
#pragma unroll
    for (int i = 0; i < 4; ++i) {
      const int gi = (r0 + 4 * q + i) * 64 + col;
      const float zm = am[i] + bm;
      const float zlv = av[i] + bv;
      out[ZM_OFF + gi] = zm;
      out[ZLV_OFF + gi] = zlv;
      out[Z_OFF + gi] = zm + eps[gi] * expf(0.5f * zlv);
    }
  }
}

// ---------------------------------------------------------------------------
// Fused decoder. 4096 WGs x 320 thr (5 waves). 32 rows/WG (one b).
// LDS = 20,992 B (g1s only; the cross-wave reduce buffer ALIASES g1s after a
// barrier) -> target 2+ WGs/CU under the empirical 64KB-occupancy-pool.
// Wave u owns n-tiles {4u..4u+3}; each b1p/b2p frag read once per WG.
// ---------------------------------------------------------------------------
__global__ __launch_bounds__(320, 4) void dec_kernel(
    const float* __restrict__ z,     // [256][64] (fp32, in d_out)
    const uint4* __restrict__ Wb,    // bf16 [512][64]
    const uint4* __restrict__ b1p,
    const uint4* __restrict__ b2p,
    const float* __restrict__ g2b,
    const float* __restrict__ hw,    // [512][300] fp32
    const float* __restrict__ hb,
    float* __restrict__ xout) {
  __shared__ u16 g1s[32 * 328];     // 20,992 B (also reused as xred after barrier)
  float* xredf = (float*)g1s;       // [5][32] floats = 640 B, aliased

  const int wg = blockIdx.x;
  const int r0 = wg << 5;           // 32 rows per WG
  const int bi = wg >> 4;           // r0 >> 9
  const int d0 = r0 & 511;
  const int tid = threadIdx.x;
  const int u = tid >> 6;           // wave: n-tiles 4u..4u+3
  const int lane = tid & 63;
  const int q = lane >> 4;
  const int c = lane & 15;

  const float* zrow = z + bi * 64;

  // ---- stage 2 ----
  bf16x8 bz[4][2];
#pragma unroll
  for (int kf = 0; kf < 2; ++kf) {
    F4 z0, z1;
    z0.v = *(const float4*)(zrow + kf * 32 + q * 8);
    z1.v = *(const float4*)(zrow + kf * 32 + q * 8 + 4);
#pragma unroll
    for (int tt = 0; tt < 4; ++tt) {
      V16 r; r.u = b1p[((4 * u + tt) * 2 + kf) * 64 + lane];
      V16 m;
#pragma unroll
      for (int j = 0; j < 4; ++j) {
        m.h[j]     = (__bf16)(bf2f(r.s[j])     * z0.f[j]);
        m.h[4 + j] = (__bf16)(bf2f(r.s[4 + j]) * z1.f[j]);
      }
      bz[tt][kf] = m.v;
    }
  }
#pragma unroll
  for (int rt = 0; rt < 2; ++rt) {
    const int rowA = rt * 16 + c;
    V16 af0, af1;
    af0.u = Wb[(d0 + rowA) * 8 + q];          // k = q*8
    af1.u = Wb[(d0 + rowA) * 8 + 4 + q];      // k = 32 + q*8
    f32x4 acc[4];
#pragma unroll
    for (int tt = 0; tt < 4; ++tt) acc[tt] = {0.f, 0.f, 0.f, 0.f};
#pragma unroll
    for (int tt = 0; tt < 4; ++tt) {
      acc[tt] = __builtin_amdgcn_mfma_f32_16x16x32_bf16(af0.v, bz[tt][0], acc[tt], 0, 0, 0);
      acc[tt] = __builtin_amdgcn_mfma_f32_16x16x32_bf16(af1.v, bz[tt][1], acc[tt], 0, 0, 0);
    }
    const int rwb = rt * 16 + 4 * q;
#pragma unroll
    for (int tt = 0; tt < 4; ++tt) {
      const int colb = (4 * u + tt) * 16 + c;
#pragma unroll
      for (int i = 0; i < 4; ++i) {
        V16 t; t.h[0] = (__bf16)fmaxf(acc[tt][i], 0.f);
        g1s[(rwb + i) * 328 + colb] = t.s[0];
      }
    }
  }
  __syncthreads();

  // ---- stage 3 ----
  f32x4 a3[4][2];   // [tt][rt]
#pragma unroll
  for (int tt = 0; tt < 4; ++tt)
#pragma unroll
    for (int rt = 0; rt < 2; ++rt) a3[tt][rt] = {0.f, 0.f, 0.f, 0.f};
  for (int s = 0; s < 10; ++s) {
    V16 b[4];
#pragma unroll
    for (int tt = 0; tt < 4; ++tt) b[tt].u = b2p[((4 * u + tt) * 10 + s) * 64 + lane];
#pragma unroll
    for (int rt = 0; rt < 2; ++rt) {
      V16 a; a.u = *(const uint4*)&g1s[(rt * 16 + c) * 328 + s * 32 + q * 8];
#pragma unroll
      for (int tt = 0; tt < 4; ++tt)
        a3[tt][rt] = __builtin_amdgcn_mfma_f32_16x16x32_bf16(a.v, b[tt].v, a3[tt][rt], 0, 0, 0);
    }
  }
  float xacc[2][4];   // [rt][i]
#pragma unroll
  for (int rt = 0; rt < 2; ++rt)
#pragma unroll
    for (int i = 0; i < 4; ++i) xacc[rt][i] = 0.f;
#pragma unroll
  for (int tt = 0; tt < 4; ++tt) {
    const int col = (4 * u + tt) * 16 + c;
    const bool inb = (col < 300);
    const float bias = inb ? g2b[col] : 0.f;
#pragma unroll
    for (int rt = 0; rt < 2; ++rt)
#pragma unroll
      for (int i = 0; i < 4; ++i) {
        const float g2v = fmaxf(a3[tt][rt][i] + bias, 0.f);
        const float h = inb ? hw[(d0 + rt * 16 + 4 * q + i) * 300 + col] : 0.f;
        xacc[rt][i] += g2v * h;
      }
  }
#pragma unroll
  for (int rt = 0; rt < 2; ++rt)
#pragma unroll
    for (int i = 0; i < 4; ++i) {
      float t = xacc[rt][i];
      t += __shfl_xor(t, 1);
      t += __shfl_xor(t, 2);
      t += __shfl_xor(t, 4);
      t += __shfl_xor(t, 8);
      xacc[rt][i] = t;
    }
  __syncthreads();   // all waves done reading g1s; safe to alias as xred
  if (c < 4) {
#pragma unroll
    for (int rt = 0; rt < 2; ++rt) {
      float t = xacc[rt][0];
      t = (c == 1) ? xacc[rt][1] : t;
      t = (c == 2) ? xacc[rt][2] : t;
      t = (c == 3) ? xacc[rt][3] : t;
      xredf[u * 32 + rt * 16 + 4 * q + c] = t;
    }
  }
  __syncthreads();
  if (tid < 32) {
    float t = hb[d0 + tid];
#pragma unroll
    for (int uu = 0; uu < 5; ++uu) t += xredf[uu * 32 + tid];
    xout[r0 + tid] = t;
  }
}

extern "C" void kernel_launch(void* const* d_in, const int* in_sizes, int n_in,
                              void* d_out, int out_size, void* d_ws, size_t ws_size,
                              hipStream_t stream) {
  const float* x   = (const float*)d_in[0];
  const float* eps = (const float*)d_in[1];
  const float* W   = (const float*)d_in[2];
  const float* e1w = (const float*)d_in[3];
  const float* e1b = (const float*)d_in[4];
  const float* e2w = (const float*)d_in[5];
  const float* e2b = (const float*)d_in[6];
  const float* zmw = (const float*)d_in[7];
  const float* zmb = (const float*)d_in[8];
  const float* zvw = (const float*)d_in[9];
  const float* zvb = (const float*)d_in[10];
  const float* g1w = (const float*)d_in[11];
  const float* g2w = (const float*)d_in[12];
  const float* g2b = (const float*)d_in[13];
  const float* hw  = (const float*)d_in[14];
  const float* hb  = (const float*)d_in[15];
  float* out = (float*)d_out;
  uint4* ws4 = (uint4*)d_ws;

  prep_kernel<<<NENC + PACK_BLOCKS, 320, 0, stream>>>(
      x, eps, e1w, e1b, e2w, e2b, zmw, zmb, zvw, zvb, g1w, g2w, W, ws4, out);
  dec_kernel<<<4096, 320, 0, stream>>>(out + Z_OFF, ws4 + WB4,
                                       ws4 + B1_OFF, ws4 + B2_OFF,
                                       g2b, hw, hb, out);
}

// Round 3
// 178.640 us; speedup vs baseline: 1.1336x; 1.1336x over previous
//
#include <hip/hip_runtime.h>

typedef unsigned short u16;
typedef unsigned int u32;

typedef __bf16 bf16x8 __attribute__((ext_vector_type(8)));
typedef float f32x4 __attribute__((ext_vector_type(4)));

union V16 { uint4 u; bf16x8 v; u16 s[8]; __bf16 h[8]; };
union F4  { float4 v; float f[4]; };

__device__ __forceinline__ float bf2f(u16 a) {
  union { u32 u; float f; } c; c.u = ((u32)a) << 16; return c.f;
}

#define Z_OFF   131072
#define ZM_OFF  147456
#define ZLV_OFF 163840

// ws layout in uint4 units.
// Fragment packs (b-frag elem j of lane: B[k=s*32+(lane>>4)*8+j][n=t*16+(lane&15)]):
#define B1_OFF 0        // gen1_w: t<20, s<2
#define B2_OFF 2560     // gen2_w: t<20, s<10
#define E1_OFF 15360    // enc1_w: t<20, s<16
#define E2_OFF 35840    // enc2_w: t<20, s<10
#define ZMP_OFF 48640   // zm_w: t<4, s<10
#define ZVP_OFF 51200   // zv_w: t<4, s<10
#define FRAG_TOTAL 53760
#define WB4  53760      // W bf16 [512][64] : 4096 uint4
#define PACK_THREADS (FRAG_TOTAL + 4096)   // 57856 = 226 * 256

__device__ __forceinline__ void pack_one(const float* __restrict__ src,
                                         int t, int s, int lane,
                                         int Nsrc, int Ksrc, int rowlen,
                                         uint4* __restrict__ dst) {
  const int n = t * 16 + (lane & 15);
  const int k0 = s * 32 + ((lane >> 4) << 3);
  V16 v;
#pragma unroll
  for (int j = 0; j < 8; ++j) {
    const int k = k0 + j;
    v.h[j] = (n < Nsrc && k < Ksrc) ? (__bf16)src[n * rowlen + k] : (__bf16)0.f;
  }
  *dst = v.u;
}

__device__ __forceinline__ void cvt8(const float* __restrict__ src, uint4* __restrict__ dst) {
  F4 a, b; a.v = *(const float4*)src; b.v = *(const float4*)(src + 4);
  V16 v;
#pragma unroll
  for (int j = 0; j < 4; ++j) { v.h[j] = (__bf16)a.f[j]; v.h[4 + j] = (__bf16)b.f[j]; }
  *dst = v.u;
}

__global__ __launch_bounds__(256) void pack_kernel(
    const float* __restrict__ g1w, const float* __restrict__ g2w,
    const float* __restrict__ e1w, const float* __restrict__ e2w,
    const float* __restrict__ zmw, const float* __restrict__ zvw,
    const float* __restrict__ W, uint4* __restrict__ ws4) {
  const int idx = blockIdx.x * 256 + threadIdx.x;
  if (idx >= PACK_THREADS) return;
  const int lane = idx & 63;
  if (idx < B2_OFF) {
    const int f = idx >> 6;
    pack_one(g1w, f >> 1, f & 1, lane, 300, 64, 64, ws4 + idx);
  } else if (idx < E1_OFF) {
    const int f = (idx - B2_OFF) >> 6;
    pack_one(g2w, f / 10, f % 10, lane, 300, 300, 300, ws4 + idx);
  } else if (idx < E2_OFF) {
    const int f = (idx - E1_OFF) >> 6;
    pack_one(e1w, f >> 4, f & 15, lane, 300, 512, 512, ws4 + idx);
  } else if (idx < ZMP_OFF) {
    const int f = (idx - E2_OFF) >> 6;
    pack_one(e2w, f / 10, f % 10, lane, 300, 300, 300, ws4 + idx);
  } else if (idx < ZVP_OFF) {
    const int f = (idx - ZMP_OFF) >> 6;
    pack_one(zmw, f / 10, f % 10, lane, 64, 300, 300, ws4 + idx);
  } else if (idx < FRAG_TOTAL) {
    const int f = (idx - ZVP_OFF) >> 6;
    pack_one(zvw, f / 10, f % 10, lane, 64, 300, 300, ws4 + idx);
  } else {
    const int i = idx - FRAG_TOTAL;
    cvt8(W + i * 8, ws4 + WB4 + i);
  }
}

// ---------------------------------------------------------------------------
// Fused encoder: 16 blocks x 320 thr. Block owns 16 rows of B; wave u owns
// n-tiles {4u..4u+3}. x staged to LDS bf16 (verified in round 1); all weight
// fragments pre-packed (verified in round 0). E1 -> E2 -> heads via LDS.
// LDS: xs 16x65 uint4 (16,640B) + h1s 16x328 u16 (10,496B) = 27,136B;
// h2s aliases xs after the E1 barrier.
// ---------------------------------------------------------------------------
__global__ __launch_bounds__(320) void enc_kernel(
    const float* __restrict__ x,   const float* __restrict__ eps,
    const uint4* __restrict__ e1p, const float* __restrict__ e1b,
    const uint4* __restrict__ e2p, const float* __restrict__ e2b,
    const uint4* __restrict__ zmp, const float* __restrict__ zmb,
    const uint4* __restrict__ zvp, const float* __restrict__ zvb,
    float* __restrict__ out) {
  __shared__ uint4 xs[16 * 65];
  __shared__ u16  h1s[16 * 328];
  u16* h2s = (u16*)xs;               // aliased after E1 barrier

  const int blk = blockIdx.x;
  const int tid = threadIdx.x;
  const int u = tid >> 6;
  const int lane = tid & 63;
  const int q = lane >> 4, c = lane & 15;
  const int r0 = blk * 16;

  // stage x rows -> LDS bf16
  for (int i = tid; i < 1024; i += 320) {
    const int row = i >> 6, kg = i & 63;
    cvt8(x + (r0 + row) * 512 + kg * 8, &xs[row * 65 + kg]);
  }
  __syncthreads();

  // E1: h1 = ReLU(x @ e1w^T + b), K=512 (16 steps)
  {
    f32x4 acc[4];
#pragma unroll
    for (int tt = 0; tt < 4; ++tt) acc[tt] = {0.f, 0.f, 0.f, 0.f};
#pragma unroll 4
    for (int s = 0; s < 16; ++s) {
      V16 a; a.u = xs[c * 65 + s * 4 + q];
#pragma unroll
      for (int tt = 0; tt < 4; ++tt) {
        V16 b; b.u = e1p[((4 * u + tt) * 16 + s) * 64 + lane];
        acc[tt] = __builtin_amdgcn_mfma_f32_16x16x32_bf16(a.v, b.v, acc[tt], 0, 0, 0);
      }
    }
#pragma unroll
    for (int tt = 0; tt < 4; ++tt) {
      const int col = (4 * u + tt) * 16 + c;
      const float bias = (col < 300) ? e1b[col] : 0.f;
#pragma unroll
      for (int i = 0; i < 4; ++i) {
        V16 t; t.h[0] = (col < 300) ? (__bf16)fmaxf(acc[tt][i] + bias, 0.f) : (__bf16)0.f;
        h1s[(4 * q + i) * 328 + col] = t.s[0];
      }
    }
  }
  __syncthreads();   // xs reads done -> safe to alias as h2s

  // E2: h2 = ReLU(h1 @ e2w^T + b), K=320 (10 steps)
  {
    f32x4 acc[4];
#pragma unroll
    for (int tt = 0; tt < 4; ++tt) acc[tt] = {0.f, 0.f, 0.f, 0.f};
#pragma unroll 2
    for (int s = 0; s < 10; ++s) {
      V16 a; a.u = *(const uint4*)&h1s[c * 328 + s * 32 + q * 8];
#pragma unroll
      for (int tt = 0; tt < 4; ++tt) {
        V16 b; b.u = e2p[((4 * u + tt) * 10 + s) * 64 + lane];
        acc[tt] = __builtin_amdgcn_mfma_f32_16x16x32_bf16(a.v, b.v, acc[tt], 0, 0, 0);
      }
    }
#pragma unroll
    for (int tt = 0; tt < 4; ++tt) {
      const int col = (4 * u + tt) * 16 + c;
      const float bias = (col < 300) ? e2b[col] : 0.f;
#pragma unroll
      for (int i = 0; i < 4; ++i) {
        V16 t; t.h[0] = (col < 300) ? (__bf16)fmaxf(acc[tt][i] + bias, 0.f) : (__bf16)0.f;
        h2s[(4 * q + i) * 328 + col] = t.s[0];
      }
    }
  }
  __syncthreads();

  // heads: zm/zlv/z; waves 0..3 own the 4 L-tiles
  if (u < 4) {
    f32x4 am = {0.f, 0.f, 0.f, 0.f}, av = {0.f, 0.f, 0.f, 0.f};
#pragma unroll 2
    for (int s = 0; s < 10; ++s) {
      V16 a; a.u = *(const uint4*)&h2s[c * 328 + s * 32 + q * 8];
      V16 bm, bv;
      bm.u = zmp[(u * 10 + s) * 64 + lane];
      bv.u = zvp[(u * 10 + s) * 64 + lane];
      am = __builtin_amdgcn_mfma_f32_16x16x32_bf16(a.v, bm.v, am, 0, 0, 0);
      av = __builtin_amdgcn_mfma_f32_16x16x32_bf16(a.v, bv.v, av, 0, 0, 0);
    }
    const int col = u * 16 + c;
    const float bm = zmb[col], bv = zvb[col];
#pragma unroll
    for (int i = 0; i < 4; ++i) {
      const int gi = (r0 + 4 * q + i) * 64 + col;
      const float zm = am[i] + bm;
      const float zlv = av[i] + bv;
      out[ZM_OFF + gi] = zm;
      out[ZLV_OFF + gi] = zlv;
      out[Z_OFF + gi] = zm + eps[gi] * expf(0.5f * zlv);
    }
  }
}

// ---------------------------------------------------------------------------
// Fused decoder (unchanged from the verified 163.7us version).
// 4096 WGs x 320 thr (5 waves). 32 rows/WG.
// ---------------------------------------------------------------------------
__global__ __launch_bounds__(320, 4) void dec_kernel(
    const float* __restrict__ z,     // [256][64] (fp32, in d_out)
    const uint4* __restrict__ Wb,    // bf16 [512][64]
    const uint4* __restrict__ b1p,
    const uint4* __restrict__ b2p,
    const float* __restrict__ g2b,
    const float* __restrict__ hw,    // [512][300] fp32
    const float* __restrict__ hb,
    float* __restrict__ xout) {
  __shared__ u16 g1s[32 * 328];     // 20,992 B (reused as xred after barrier)
  float* xredf = (float*)g1s;

  const int wg = blockIdx.x;
  const int r0 = wg << 5;
  const int bi = wg >> 4;
  const int d0 = r0 & 511;
  const int tid = threadIdx.x;
  const int u = tid >> 6;
  const int lane = tid & 63;
  const int q = lane >> 4;
  const int c = lane & 15;

  const float* zrow = z + bi * 64;

  // ---- stage 2 ----
  bf16x8 bz[4][2];
#pragma unroll
  for (int kf = 0; kf < 2; ++kf) {
    F4 z0, z1;
    z0.v = *(const float4*)(zrow + kf * 32 + q * 8);
    z1.v = *(const float4*)(zrow + kf * 32 + q * 8 + 4);
#pragma unroll
    for (int tt = 0; tt < 4; ++tt) {
      V16 r; r.u = b1p[((4 * u + tt) * 2 + kf) * 64 + lane];
      V16 m;
#pragma unroll
      for (int j = 0; j < 4; ++j) {
        m.h[j]     = (__bf16)(bf2f(r.s[j])     * z0.f[j]);
        m.h[4 + j] = (__bf16)(bf2f(r.s[4 + j]) * z1.f[j]);
      }
      bz[tt][kf] = m.v;
    }
  }
#pragma unroll
  for (int rt = 0; rt < 2; ++rt) {
    const int rowA = rt * 16 + c;
    V16 af0, af1;
    af0.u = Wb[(d0 + rowA) * 8 + q];
    af1.u = Wb[(d0 + rowA) * 8 + 4 + q];
    f32x4 acc[4];
#pragma unroll
    for (int tt = 0; tt < 4; ++tt) acc[tt] = {0.f, 0.f, 0.f, 0.f};
#pragma unroll
    for (int tt = 0; tt < 4; ++tt) {
      acc[tt] = __builtin_amdgcn_mfma_f32_16x16x32_bf16(af0.v, bz[tt][0], acc[tt], 0, 0, 0);
      acc[tt] = __builtin_amdgcn_mfma_f32_16x16x32_bf16(af1.v, bz[tt][1], acc[tt], 0, 0, 0);
    }
    const int rwb = rt * 16 + 4 * q;
#pragma unroll
    for (int tt = 0; tt < 4; ++tt) {
      const int colb = (4 * u + tt) * 16 + c;
#pragma unroll
      for (int i = 0; i < 4; ++i) {
        V16 t; t.h[0] = (__bf16)fmaxf(acc[tt][i], 0.f);
        g1s[(rwb + i) * 328 + colb] = t.s[0];
      }
    }
  }
  __syncthreads();

  // ---- stage 3 ----
  f32x4 a3[4][2];
#pragma unroll
  for (int tt = 0; tt < 4; ++tt)
#pragma unroll
    for (int rt = 0; rt < 2; ++rt) a3[tt][rt] = {0.f, 0.f, 0.f, 0.f};
  for (int s = 0; s < 10; ++s) {
    V16 b[4];
#pragma unroll
    for (int tt = 0; tt < 4; ++tt) b[tt].u = b2p[((4 * u + tt) * 10 + s) * 64 + lane];
#pragma unroll
    for (int rt = 0; rt < 2; ++rt) {
      V16 a; a.u = *(const uint4*)&g1s[(rt * 16 + c) * 328 + s * 32 + q * 8];
#pragma unroll
      for (int tt = 0; tt < 4; ++tt)
        a3[tt][rt] = __builtin_amdgcn_mfma_f32_16x16x32_bf16(a.v, b[tt].v, a3[tt][rt], 0, 0, 0);
    }
  }
  float xacc[2][4];
#pragma unroll
  for (int rt = 0; rt < 2; ++rt)
#pragma unroll
    for (int i = 0; i < 4; ++i) xacc[rt][i] = 0.f;
#pragma unroll
  for (int tt = 0; tt < 4; ++tt) {
    const int col = (4 * u + tt) * 16 + c;
    const bool inb = (col < 300);
    const float bias = inb ? g2b[col] : 0.f;
#pragma unroll
    for (int rt = 0; rt < 2; ++rt)
#pragma unroll
      for (int i = 0; i < 4; ++i) {
        const float g2v = fmaxf(a3[tt][rt][i] + bias, 0.f);
        const float h = inb ? hw[(d0 + rt * 16 + 4 * q + i) * 300 + col] : 0.f;
        xacc[rt][i] += g2v * h;
      }
  }
#pragma unroll
  for (int rt = 0; rt < 2; ++rt)
#pragma unroll
    for (int i = 0; i < 4; ++i) {
      float t = xacc[rt][i];
      t += __shfl_xor(t, 1);
      t += __shfl_xor(t, 2);
      t += __shfl_xor(t, 4);
      t += __shfl_xor(t, 8);
      xacc[rt][i] = t;
    }
  __syncthreads();
  if (c < 4) {
#pragma unroll
    for (int rt = 0; rt < 2; ++rt) {
      float t = xacc[rt][0];
      t = (c == 1) ? xacc[rt][1] : t;
      t = (c == 2) ? xacc[rt][2] : t;
      t = (c == 3) ? xacc[rt][3] : t;
      xredf[u * 32 + rt * 16 + 4 * q + c] = t;
    }
  }
  __syncthreads();
  if (tid < 32) {
    float t = hb[d0 + tid];
#pragma unroll
    for (int uu = 0; uu < 5; ++uu) t += xredf[uu * 32 + tid];
    xout[r0 + tid] = t;
  }
}

extern "C" void kernel_launch(void* const* d_in, const int* in_sizes, int n_in,
                              void* d_out, int out_size, void* d_ws, size_t ws_size,
                              hipStream_t stream) {
  const float* x   = (const float*)d_in[0];
  const float* eps = (const float*)d_in[1];
  const float* W   = (const float*)d_in[2];
  const float* e1w = (const float*)d_in[3];
  const float* e1b = (const float*)d_in[4];
  const float* e2w = (const float*)d_in[5];
  const float* e2b = (const float*)d_in[6];
  const float* zmw = (const float*)d_in[7];
  const float* zmb = (const float*)d_in[8];
  const float* zvw = (const float*)d_in[9];
  const float* zvb = (const float*)d_in[10];
  const float* g1w = (const float*)d_in[11];
  const float* g2w = (const float*)d_in[12];
  const float* g2b = (const float*)d_in[13];
  const float* hw  = (const float*)d_in[14];
  const float* hb  = (const float*)d_in[15];
  float* out = (float*)d_out;
  uint4* ws4 = (uint4*)d_ws;

  pack_kernel<<<PACK_THREADS / 256, 256, 0, stream>>>(
      g1w, g2w, e1w, e2w, zmw, zvw, W, ws4);
  enc_kernel<<<16, 320, 0, stream>>>(x, eps,
                                     ws4 + E1_OFF, e1b, ws4 + E2_OFF, e2b,
                                     ws4 + ZMP_OFF, zmb, ws4 + ZVP_OFF, zvb, out);
  dec_kernel<<<4096, 320, 0, stream>>>(out + Z_OFF, ws4 + WB4,
                                       ws4 + B1_OFF, ws4 + B2_OFF,
                                       g2b, hw, hb, out);
}

// Round 4
// 169.350 us; speedup vs baseline: 1.1958x; 1.0549x over previous
//
#include <hip/hip_runtime.h>

typedef unsigned short u16;
typedef unsigned int u32;

typedef __bf16 bf16x8 __attribute__((ext_vector_type(8)));
typedef float f32x4 __attribute__((ext_vector_type(4)));

union V16 { uint4 u; bf16x8 v; u16 s[8]; __bf16 h[8]; };
union F4  { float4 v; float f[4]; };

__device__ __forceinline__ float bf2f(u16 a) {
  union { u32 u; float f; } c; c.u = ((u32)a) << 16; return c.f;
}

#define Z_OFF   131072
#define ZM_OFF  147456
#define ZLV_OFF 163840

// ws layout in uint4 units (R0 layout, verbatim).
#define B1_OFF 0        // gen1_w: t<20, s<2
#define B2_OFF 2560     // gen2_w: t<20, s<10
#define E1_OFF 15360    // enc1_w: t<20, s<16
#define E2_OFF 35840    // enc2_w: t<20, s<10
#define ZMP_OFF 48640   // zm_w: t<4, s<10
#define ZVP_OFF 51200   // zv_w: t<4, s<10
#define FRAG_TOTAL 53760
#define WB4  53760      // W bf16 [512][64]     : 4096 uint4
#define XB4  57856      // x bf16 [256][512]    : 16384 uint4
#define H1_4 74240      // h1 bf16 [256][320]   : 10240 uint4
#define H2_4 84480      // h2 bf16 [256][320]   : 10240 uint4
#define PACK_THREADS (FRAG_TOTAL + 4096 + 16384)   // 74240

__device__ __forceinline__ void pack_one(const float* __restrict__ src,
                                         int t, int s, int lane,
                                         int Nsrc, int Ksrc, int rowlen,
                                         uint4* __restrict__ dst) {
  const int n = t * 16 + (lane & 15);
  const int k0 = s * 32 + ((lane >> 4) << 3);
  V16 v;
#pragma unroll
  for (int j = 0; j < 8; ++j) {
    const int k = k0 + j;
    v.h[j] = (n < Nsrc && k < Ksrc) ? (__bf16)src[n * rowlen + k] : (__bf16)0.f;
  }
  *dst = v.u;
}

__device__ __forceinline__ void cvt8(const float* __restrict__ src, uint4* __restrict__ dst) {
  F4 a, b; a.v = *(const float4*)src; b.v = *(const float4*)(src + 4);
  V16 v;
#pragma unroll
  for (int j = 0; j < 4; ++j) { v.h[j] = (__bf16)a.f[j]; v.h[4 + j] = (__bf16)b.f[j]; }
  *dst = v.u;
}

__global__ __launch_bounds__(256) void pack_kernel(
    const float* __restrict__ g1w, const float* __restrict__ g2w,
    const float* __restrict__ e1w, const float* __restrict__ e2w,
    const float* __restrict__ zmw, const float* __restrict__ zvw,
    const float* __restrict__ W,   const float* __restrict__ x,
    uint4* __restrict__ ws4) {
  const int idx = blockIdx.x * 256 + threadIdx.x;
  if (idx >= PACK_THREADS) return;
  const int lane = idx & 63;
  if (idx < B2_OFF) {
    const int f = (idx - B1_OFF) >> 6;
    pack_one(g1w, f >> 1, f & 1, lane, 300, 64, 64, ws4 + idx);
  } else if (idx < E1_OFF) {
    const int f = (idx - B2_OFF) >> 6;
    pack_one(g2w, f / 10, f % 10, lane, 300, 300, 300, ws4 + idx);
  } else if (idx < E2_OFF) {
    const int f = (idx - E1_OFF) >> 6;
    pack_one(e1w, f >> 4, f & 15, lane, 300, 512, 512, ws4 + idx);
  } else if (idx < ZMP_OFF) {
    const int f = (idx - E2_OFF) >> 6;
    pack_one(e2w, f / 10, f % 10, lane, 300, 300, 300, ws4 + idx);
  } else if (idx < ZVP_OFF) {
    const int f = (idx - ZMP_OFF) >> 6;
    pack_one(zmw, f / 10, f % 10, lane, 64, 300, 300, ws4 + idx);
  } else if (idx < FRAG_TOTAL) {
    const int f = (idx - ZVP_OFF) >> 6;
    pack_one(zvw, f / 10, f % 10, lane, 64, 300, 300, ws4 + idx);
  } else if (idx < FRAG_TOTAL + 4096) {
    const int i = idx - FRAG_TOTAL;
    cvt8(W + i * 8, ws4 + WB4 + i);
  } else {
    const int i = idx - FRAG_TOTAL - 4096;
    cvt8(x + i * 8, ws4 + XB4 + i);
  }
}

// enc1: 320 WGs (rt 16 x nt 20) x 64 thr (R0 verbatim).
__global__ __launch_bounds__(64) void enc1_kernel(
    const uint4* __restrict__ xb, const uint4* __restrict__ e1p,
    const float* __restrict__ e1b, u16* __restrict__ h1) {
  const int wg = blockIdx.x;
  const int rt = wg / 20, nt = wg % 20;
  const int lane = threadIdx.x, q = lane >> 4, c = lane & 15;
  f32x4 acc = {0.f, 0.f, 0.f, 0.f};
  const int arow = rt * 16 + c;
#pragma unroll
  for (int s = 0; s < 16; ++s) {
    V16 a, b;
    a.u = xb[arow * 64 + s * 4 + q];
    b.u = e1p[(nt * 16 + s) * 64 + lane];
    acc = __builtin_amdgcn_mfma_f32_16x16x32_bf16(a.v, b.v, acc, 0, 0, 0);
  }
  const int col = nt * 16 + c;
  const float bias = (col < 300) ? e1b[col] : 0.f;
#pragma unroll
  for (int i = 0; i < 4; ++i) {
    const int row = rt * 16 + 4 * q + i;
    V16 t; t.h[0] = (col < 300) ? (__bf16)fmaxf(acc[i] + bias, 0.f) : (__bf16)0.f;
    h1[row * 320 + col] = t.s[0];
  }
}

// enc2: same shape, K=320 (10 steps), A from h1, writes h2 (R0 verbatim).
__global__ __launch_bounds__(64) void enc2_kernel(
    const uint4* __restrict__ h1, const uint4* __restrict__ e2p,
    const float* __restrict__ e2b, u16* __restrict__ h2) {
  const int wg = blockIdx.x;
  const int rt = wg / 20, nt = wg % 20;
  const int lane = threadIdx.x, q = lane >> 4, c = lane & 15;
  f32x4 acc = {0.f, 0.f, 0.f, 0.f};
  const int arow = rt * 16 + c;
#pragma unroll
  for (int s = 0; s < 10; ++s) {
    V16 a, b;
    a.u = h1[arow * 40 + s * 4 + q];
    b.u = e2p[(nt * 10 + s) * 64 + lane];
    acc = __builtin_amdgcn_mfma_f32_16x16x32_bf16(a.v, b.v, acc, 0, 0, 0);
  }
  const int col = nt * 16 + c;
  const float bias = (col < 300) ? e2b[col] : 0.f;
#pragma unroll
  for (int i = 0; i < 4; ++i) {
    const int row = rt * 16 + 4 * q + i;
    V16 t; t.h[0] = (col < 300) ? (__bf16)fmaxf(acc[i] + bias, 0.f) : (__bf16)0.f;
    h2[row * 320 + col] = t.s[0];
  }
}

// heads: 64 WGs (rt 16 x t 4) x 64 thr (R0 verbatim).
__global__ __launch_bounds__(64) void ench_kernel(
    const uint4* __restrict__ h2, const float* __restrict__ eps,
    const uint4* __restrict__ zmp, const float* __restrict__ zmb,
    const uint4* __restrict__ zvp, const float* __restrict__ zvb,
    float* __restrict__ out) {
  const int wg = blockIdx.x;
  const int rt = wg >> 2, t = wg & 3;
  const int lane = threadIdx.x, q = lane >> 4, c = lane & 15;
  f32x4 am = {0.f, 0.f, 0.f, 0.f}, av = {0.f, 0.f, 0.f, 0.f};
  const int arow = rt * 16 + c;
#pragma unroll
  for (int s = 0; s < 10; ++s) {
    V16 a, bm, bv;
    a.u = h2[arow * 40 + s * 4 + q];
    bm.u = zmp[(t * 10 + s) * 64 + lane];
    bv.u = zvp[(t * 10 + s) * 64 + lane];
    am = __builtin_amdgcn_mfma_f32_16x16x32_bf16(a.v, bm.v, am, 0, 0, 0);
    av = __builtin_amdgcn_mfma_f32_16x16x32_bf16(a.v, bv.v, av, 0, 0, 0);
  }
  const int col = t * 16 + c;
  const float bm = zmb[col], bv = zvb[col];
#pragma unroll
  for (int i = 0; i < 4; ++i) {
    const int gi = (rt * 16 + 4 * q + i) * 64 + col;
    const float zm = am[i] + bm;
    const float zlv = av[i] + bv;
    out[ZM_OFF + gi] = zm;
    out[ZLV_OFF + gi] = zlv;
    out[Z_OFF + gi] = zm + eps[gi] * expf(0.5f * zlv);
  }
}

// ---------------------------------------------------------------------------
// Fused decoder, 64 rows/WG: 2048 WGs x 320 thr (5 waves).
// Each b2p fragment now feeds 4 MFMAs (rt=0..3) instead of 2 -> b2p L2
// traffic halves (819->410MB) and per-WG fixed costs halve.
// LDS = 64x328 bf16 = 41,984B -> 3 blocks/CU; VGPR capped <=128 via
// __launch_bounds__(320,4) -> 16-wave quantum still admits 3 blocks.
// ---------------------------------------------------------------------------
__global__ __launch_bounds__(320, 4) void dec_kernel(
    const float* __restrict__ z,     // [256][64] (fp32, in d_out)
    const uint4* __restrict__ Wb,    // bf16 [512][64]
    const uint4* __restrict__ b1p,
    const uint4* __restrict__ b2p,
    const float* __restrict__ g2b,
    const float* __restrict__ hw,    // [512][300] fp32
    const float* __restrict__ hb,
    float* __restrict__ xout) {
  __shared__ u16 g1s[64 * 328];     // 41,984 B (reused as xred after barrier)
  float* xredf = (float*)g1s;       // [5][64] floats, aliased

  const int wg = blockIdx.x;
  const int r0 = wg << 6;           // 64 rows per WG
  const int bi = wg >> 3;           // r0 >> 9
  const int d0 = r0 & 511;          // {0,64,...,448}
  const int tid = threadIdx.x;
  const int u = tid >> 6;           // wave: n-tiles 4u..4u+3
  const int lane = tid & 63;
  const int q = lane >> 4;
  const int c = lane & 15;

  const float* zrow = z + bi * 64;

  // preload s=0 b2p fragments; latency hides under stage 2 + barrier
  V16 bcur[4];
#pragma unroll
  for (int tt = 0; tt < 4; ++tt)
    bcur[tt].u = b2p[((4 * u + tt) * 10 + 0) * 64 + lane];

  // ---- stage 2: g1 = ReLU((z .* W-rows) @ gen1_w^T) ----
  {
    bf16x8 bz[4][2];
#pragma unroll
    for (int kf = 0; kf < 2; ++kf) {
      F4 z0, z1;
      z0.v = *(const float4*)(zrow + kf * 32 + q * 8);
      z1.v = *(const float4*)(zrow + kf * 32 + q * 8 + 4);
#pragma unroll
      for (int tt = 0; tt < 4; ++tt) {
        V16 r; r.u = b1p[((4 * u + tt) * 2 + kf) * 64 + lane];
        V16 m;
#pragma unroll
        for (int j = 0; j < 4; ++j) {
          m.h[j]     = (__bf16)(bf2f(r.s[j])     * z0.f[j]);
          m.h[4 + j] = (__bf16)(bf2f(r.s[4 + j]) * z1.f[j]);
        }
        bz[tt][kf] = m.v;
      }
    }
#pragma unroll
    for (int rt = 0; rt < 4; ++rt) {
      const int rowA = rt * 16 + c;
      V16 af0, af1;
      af0.u = Wb[(d0 + rowA) * 8 + q];          // k = q*8
      af1.u = Wb[(d0 + rowA) * 8 + 4 + q];      // k = 32 + q*8
      f32x4 acc[4];
#pragma unroll
      for (int tt = 0; tt < 4; ++tt) acc[tt] = {0.f, 0.f, 0.f, 0.f};
#pragma unroll
      for (int tt = 0; tt < 4; ++tt) {
        acc[tt] = __builtin_amdgcn_mfma_f32_16x16x32_bf16(af0.v, bz[tt][0], acc[tt], 0, 0, 0);
        acc[tt] = __builtin_amdgcn_mfma_f32_16x16x32_bf16(af1.v, bz[tt][1], acc[tt], 0, 0, 0);
      }
      const int rwb = rt * 16 + 4 * q;
#pragma unroll
      for (int tt = 0; tt < 4; ++tt) {
        const int colb = (4 * u + tt) * 16 + c;
#pragma unroll
        for (int i = 0; i < 4; ++i) {
          V16 t; t.h[0] = (__bf16)fmaxf(acc[tt][i], 0.f);
          g1s[(rwb + i) * 328 + colb] = t.s[0];
        }
      }
    }
  }
  __syncthreads();

  // ---- stage 3: g2 = ReLU(g1 @ gen2_w^T + b) with 4 A-tiles per b2p load --
  f32x4 a3[4][4];   // [tt][rt]
#pragma unroll
  for (int tt = 0; tt < 4; ++tt)
#pragma unroll
    for (int rt = 0; rt < 4; ++rt) a3[tt][rt] = {0.f, 0.f, 0.f, 0.f};
#pragma unroll 2
  for (int s = 0; s < 10; ++s) {
    V16 b[4];
    if (s == 0) {
#pragma unroll
      for (int tt = 0; tt < 4; ++tt) b[tt] = bcur[tt];
    } else {
#pragma unroll
      for (int tt = 0; tt < 4; ++tt) b[tt].u = b2p[((4 * u + tt) * 10 + s) * 64 + lane];
    }
#pragma unroll
    for (int rt = 0; rt < 4; ++rt) {
      V16 a; a.u = *(const uint4*)&g1s[(rt * 16 + c) * 328 + s * 32 + q * 8];
#pragma unroll
      for (int tt = 0; tt < 4; ++tt)
        a3[tt][rt] = __builtin_amdgcn_mfma_f32_16x16x32_bf16(a.v, b[tt].v, a3[tt][rt], 0, 0, 0);
    }
  }

  // ---- epilogue: x_mean partial = sum_h g2 .* head_w ----
  float xacc[4][4];   // [rt][i]
#pragma unroll
  for (int rt = 0; rt < 4; ++rt)
#pragma unroll
    for (int i = 0; i < 4; ++i) xacc[rt][i] = 0.f;
#pragma unroll
  for (int tt = 0; tt < 4; ++tt) {
    const int col = (4 * u + tt) * 16 + c;
    const bool inb = (col < 300);
    const float bias = inb ? g2b[col] : 0.f;
#pragma unroll
    for (int rt = 0; rt < 4; ++rt)
#pragma unroll
      for (int i = 0; i < 4; ++i) {
        const float g2v = fmaxf(a3[tt][rt][i] + bias, 0.f);
        const float h = inb ? hw[(d0 + rt * 16 + 4 * q + i) * 300 + col] : 0.f;
        xacc[rt][i] += g2v * h;
      }
  }
#pragma unroll
  for (int rt = 0; rt < 4; ++rt)
#pragma unroll
    for (int i = 0; i < 4; ++i) {
      float t = xacc[rt][i];
      t += __shfl_xor(t, 1);
      t += __shfl_xor(t, 2);
      t += __shfl_xor(t, 4);
      t += __shfl_xor(t, 8);
      xacc[rt][i] = t;
    }
  __syncthreads();   // all waves done reading g1s; safe to alias as xred
  if (c < 4) {
#pragma unroll
    for (int rt = 0; rt < 4; ++rt) {
      float t = xacc[rt][0];
      t = (c == 1) ? xacc[rt][1] : t;
      t = (c == 2) ? xacc[rt][2] : t;
      t = (c == 3) ? xacc[rt][3] : t;
      xredf[u * 64 + rt * 16 + 4 * q + c] = t;
    }
  }
  __syncthreads();
  if (tid < 64) {
    float t = hb[d0 + tid];
#pragma unroll
    for (int uu = 0; uu < 5; ++uu) t += xredf[uu * 64 + tid];
    xout[r0 + tid] = t;
  }
}

extern "C" void kernel_launch(void* const* d_in, const int* in_sizes, int n_in,
                              void* d_out, int out_size, void* d_ws, size_t ws_size,
                              hipStream_t stream) {
  const float* x   = (const float*)d_in[0];
  const float* eps = (const float*)d_in[1];
  const float* W   = (const float*)d_in[2];
  const float* e1w = (const float*)d_in[3];
  const float* e1b = (const float*)d_in[4];
  const float* e2w = (const float*)d_in[5];
  const float* e2b = (const float*)d_in[6];
  const float* zmw = (const float*)d_in[7];
  const float* zmb = (const float*)d_in[8];
  const float* zvw = (const float*)d_in[9];
  const float* zvb = (const float*)d_in[10];
  const float* g1w = (const float*)d_in[11];
  const float* g2w = (const float*)d_in[12];
  const float* g2b = (const float*)d_in[13];
  const float* hw  = (const float*)d_in[14];
  const float* hb  = (const float*)d_in[15];
  float* out = (float*)d_out;
  uint4* ws4 = (uint4*)d_ws;

  pack_kernel<<<(PACK_THREADS + 255) / 256, 256, 0, stream>>>(
      g1w, g2w, e1w, e2w, zmw, zvw, W, x, ws4);
  enc1_kernel<<<320, 64, 0, stream>>>(ws4 + XB4, ws4 + E1_OFF, e1b, (u16*)(ws4 + H1_4));
  enc2_kernel<<<320, 64, 0, stream>>>(ws4 + H1_4, ws4 + E2_OFF, e2b, (u16*)(ws4 + H2_4));
  ench_kernel<<<64, 64, 0, stream>>>(ws4 + H2_4, eps,
                                     ws4 + ZMP_OFF, zmb, ws4 + ZVP_OFF, zvb, out);
  dec_kernel<<<2048, 320, 0, stream>>>(out + Z_OFF, ws4 + WB4,
                                       ws4 + B1_OFF, ws4 + B2_OFF,
                                       g2b, hw, hb, out);
}